// Round 3
// baseline (468.078 us; speedup 1.0000x reference)
//
#include <hip/hip_runtime.h>

typedef __attribute__((ext_vector_type(4))) short bf16x4;
typedef __attribute__((ext_vector_type(8))) short bf16x8;
typedef __attribute__((ext_vector_type(16))) float f32x16;
typedef __attribute__((ext_vector_type(4))) float f32x4;
typedef __attribute__((ext_vector_type(4))) unsigned int u32x4;

__device__ __forceinline__ unsigned short f2bf(float f) {
    unsigned int u = __builtin_bit_cast(unsigned int, f);
    u += 0x7fffu + ((u >> 16) & 1u);   // RNE (inputs are finite normals)
    return (unsigned short)(u >> 16);
}

#define PA 212   // lds_a pitch (bf16): 424 B/row -> 106 dw, %32=10 (2-way only), %8B==0

// K-split: 900 chunks = (i:2, c_out:6, pc:75), chunk K = 200 contiguous pl (pad->208 vk).
// Block b owns chunks 4b..4b+3.  x reads: 3 c_in streams of 800 B contiguous per (n,chunk).
// Sibling blocks (same i,pc, c_out triple) re-read the same x lines -> L3 hits.
__device__ __forceinline__ void chunk_params(int ch, long& KB, long& XB, int& d) {
    int i_ = ch / 450, r_ = ch - 450 * i_;
    int c_ = r_ / 75,  pc_ = r_ - 75 * c_;
    KB = (long)(i_ * 6 + c_) * 15000 + pc_ * 200;              // W-row / output-K base
    XB = (long)i_ * 90000 + (c_ >= 3 ? 45000 : 0) + pc_ * 200; // x base (c_in chunk)
    d  = c_ - (c_ >= 3 ? 3 : 0);                               // RT column
}

// W prefetch: 1 item/thread: rows (pl, pl+1), 4 cols -> 2 x f32x4
#define ISSUE(R, KB, SUB) do { \
    const int vk2_ = tid >> 6; \
    const int pl_  = (SUB)*16 + vk2_*2; \
    f32x4 q0_ = {0.f,0.f,0.f,0.f}, q1_ = {0.f,0.f,0.f,0.f}; \
    if (pl_ < 200) { \
        const float* wr_ = W + ((KB) + (long)pl_)*256 + (tid & 63)*4; \
        q0_ = *(const f32x4*)wr_; \
        q1_ = *(const f32x4*)(wr_ + 256); \
    } \
    R[0]=q0_.x; R[1]=q0_.y; R[2]=q0_.z; R[3]=q0_.w; \
    R[4]=q1_.x; R[5]=q1_.y; R[6]=q1_.z; R[7]=q1_.w; \
} while (0)

#define PACK(R, BUF) do { \
    u32x4 pw_; \
    pw_.x = (unsigned)f2bf(R[0]) | ((unsigned)f2bf(R[4]) << 16); \
    pw_.y = (unsigned)f2bf(R[1]) | ((unsigned)f2bf(R[5]) << 16); \
    pw_.z = (unsigned)f2bf(R[2]) | ((unsigned)f2bf(R[6]) << 16); \
    pw_.w = (unsigned)f2bf(R[3]) | ((unsigned)f2bf(R[7]) << 16); \
    *((u32x4*)&lds_b[BUF][(tid >> 6)*256 + (tid & 63)*4]) = pw_; \
} while (0)

// A stage: 12800 quad-items (256 n x 50 pl-quads), 3 contiguous 800B streams, 1 c_out
#define ASTAGE(XB, A0, A1, A2) do { \
    _Pragma("unroll 5") \
    for (int k_ = 0; k_ < 25; ++k_) { \
        const int it_ = k_*512 + tid; \
        const int n_  = (int)(((unsigned)it_ * 5243u) >> 18);  /* it/50 exact */ \
        const int q_  = it_ - n_*50; \
        const float* px_ = x + (long)n_*180000 + (XB) + q_*4; \
        const f32x4 c0_ = *(const f32x4*)px_; \
        const f32x4 c1_ = *(const f32x4*)(px_ + 15000); \
        const f32x4 c2_ = *(const f32x4*)(px_ + 30000); \
        bf16x4 o_; \
        _Pragma("unroll") \
        for (int e_ = 0; e_ < 4; ++e_) \
            o_[e_] = (short)f2bf(c0_[e_]*(A0) + c1_[e_]*(A1) + c2_[e_]*(A2)); \
        *(bf16x4*)&lds_a[n_*PA + q_*4] = o_; \
    } \
} while (0)

#define MFMASTEP(J, BUFSEL) do { \
    const unsigned int* bb_ = lds_b[BUFSEL]; \
    const int kb_ = (J)*16 + lh*8; \
    bf16x8 af_[2]; \
    _Pragma("unroll") \
    for (int fm_ = 0; fm_ < 2; ++fm_) { \
        const unsigned short* pa_ = &lds_a[(m0 + fm_*32 + lm)*PA + kb_]; \
        bf16x4 alo_ = *(const bf16x4*)pa_; \
        bf16x4 ahi_ = *(const bf16x4*)(pa_ + 4); \
        af_[fm_] = __builtin_shufflevector(alo_, ahi_, 0,1,2,3,4,5,6,7); \
    } \
    _Pragma("unroll") \
    for (int fd_ = 0; fd_ < 4; ++fd_) { \
        const int db_ = d0 + fd_*32 + lm; \
        const int v2_ = lh*4; \
        u32x4 bw_ = { bb_[(v2_+0)*256 + db_], bb_[(v2_+1)*256 + db_], \
                      bb_[(v2_+2)*256 + db_], bb_[(v2_+3)*256 + db_] }; \
        bf16x8 bv_ = __builtin_bit_cast(bf16x8, bw_); \
        _Pragma("unroll") \
        for (int fm_ = 0; fm_ < 2; ++fm_) \
            acc[fm_][fd_] = __builtin_amdgcn_mfma_f32_32x32x16_bf16(af_[fm_], bv_, acc[fm_][fd_], 0, 0, 0); \
    } \
} while (0)

__global__ __launch_bounds__(512, 2) void gemm_kernel(
    const float* __restrict__ x,
    const float* __restrict__ rw, const float* __restrict__ sw, const float* __restrict__ cw,
    const float* __restrict__ W,
    const float* __restrict__ Rr, const float* __restrict__ Rs, const float* __restrict__ Rc,
    float* __restrict__ P)
{
    __shared__ unsigned short lds_a[256 * PA];      // 108544 B, bf16 feats [n][vk 0..207]
    __shared__ unsigned int   lds_b[2][8 * 256];    // 2 x 8KB: packed bf16 pairs [vk2][d]

    const int tid = threadIdx.x;
    const int blk = blockIdx.x;

    // ---- Rtot = (R_rotate*rw) @ (R_shear*sw) @ (R_scale*cw), row-major [c_in][c_out] ----
    float Ar[9], Br[9], Cr[9], T1[9], RT[9];
    #pragma unroll
    for (int e = 0; e < 9; ++e) {
        Ar[e] = Rr[e] * rw[e];
        Br[e] = Rs[e] * sw[e];
        Cr[e] = Rc[e] * cw[e];
    }
    #pragma unroll
    for (int r = 0; r < 3; ++r)
        #pragma unroll
        for (int c = 0; c < 3; ++c)
            T1[r*3+c] = Ar[r*3+0]*Br[0*3+c] + Ar[r*3+1]*Br[1*3+c] + Ar[r*3+2]*Br[2*3+c];
    #pragma unroll
    for (int r = 0; r < 3; ++r)
        #pragma unroll
        for (int c = 0; c < 3; ++c)
            RT[r*3+c] = T1[r*3+0]*Cr[0*3+c] + T1[r*3+1]*Cr[1*3+c] + T1[r*3+2]*Cr[2*3+c];

    // ---- zero A pad cols 200..207 once (ASTAGE only writes cols < 200) ----
    if (tid < 256) {
        bf16x4 zz = (bf16x4)0;
        *((bf16x4*)&lds_a[tid*PA + 200]) = zz;
        *((bf16x4*)&lds_a[tid*PA + 204]) = zz;
    }

    const int w  = tid >> 6, l = tid & 63;
    const int lm = l & 31,  lh = l >> 5;
    const int m0 = (w >> 1) * 64;     // 4 wave-rows
    const int d0 = (w & 1) * 128;     // 2 wave-cols

    f32x16 acc[2][4];
    #pragma unroll
    for (int fm = 0; fm < 2; ++fm)
        #pragma unroll
        for (int fd = 0; fd < 4; ++fd)
            acc[fm][fd] = (f32x16)0.0f;

    float RW0[8], RW1[8];

    // ---- prologue: W(0),W(1) in flight; A-stage chunk 0 under W(0) latency ----
    {
        long KB0, XB0; int dd0;
        chunk_params(4*blk, KB0, XB0, dd0);
        ISSUE(RW0, KB0, 0);
        ASTAGE(XB0, RT[dd0], RT[3+dd0], RT[6+dd0]);
        ISSUE(RW1, KB0, 1);
        PACK(RW0, 0);
    }
    __syncthreads();

    // ---- 4 chunks x 13 substeps of 16 vk; depth-2 W prefetch across barriers ----
    for (int cc = 0; cc < 4; ++cc) {
        long KB, XB; int dd;
        chunk_params(4*blk + cc, KB, XB, dd);
        for (int j = 0; j < 13; ++j) {
            const int u = cc*13 + j;
            if (u + 2 < 52) {
                const int u2 = u + 2;
                const int cc2 = u2 / 13, j2 = u2 - 13*cc2;
                long KB2, XB2; int dd2;
                chunk_params(4*blk + cc2, KB2, XB2, dd2);
                if (u & 1) ISSUE(RW1, KB2, j2);
                else       ISSUE(RW0, KB2, j2);
            }
            if (j == 0 && cc > 0) {
                ASTAGE(XB, RT[dd], RT[3+dd], RT[6+dd]);
                __syncthreads();
            }
            MFMASTEP(j, (u & 1));
            if (u < 51) {
                if (u & 1) PACK(RW0, ((u+1) & 1));
                else       PACK(RW1, ((u+1) & 1));
            }
            __syncthreads();
        }
    }

    // ---- write fp32 partial C tile ----
    float* Pb = P + (size_t)blk * 65536;
    #pragma unroll
    for (int fm = 0; fm < 2; ++fm)
        #pragma unroll
        for (int fd = 0; fd < 4; ++fd)
            #pragma unroll
            for (int r = 0; r < 16; ++r) {
                int row = m0 + fm*32 + (r & 3) + 8*(r >> 2) + 4*lh;
                int col = d0 + fd*32 + lm;
                Pb[row*256 + col] = acc[fm][fd][r];
            }
}

// Sum 225 partials + bias, write z twice to out, write zhat (row-normalized) to Z.
__global__ __launch_bounds__(1024) void reduce_kernel(
    const float* __restrict__ P, const float* __restrict__ bias,
    float* __restrict__ out, float* __restrict__ Z)
{
    __shared__ float sred[4][256];
    __shared__ float wsum[16];
    const int n = blockIdx.x;
    const int tid = threadIdx.x;
    const int sg = tid >> 8, d = tid & 255;

    const float* p = P + (size_t)n*256 + d;
    float z = 0.f;
    #pragma unroll 8
    for (int s = sg; s < 225; s += 4) z += p[(size_t)s * 65536];
    sred[sg][d] = z;
    __syncthreads();

    float zf = 0.f;
    if (sg == 0) zf = sred[0][d] + sred[1][d] + sred[2][d] + sred[3][d] + bias[d];
    float sq = zf * zf;
    #pragma unroll
    for (int off = 32; off > 0; off >>= 1) sq += __shfl_down(sq, off, 64);
    if ((tid & 63) == 0) wsum[tid >> 6] = sq;
    __syncthreads();
    if (sg == 0) {
        float tot = wsum[0] + wsum[1] + wsum[2] + wsum[3];  // waves 0..3 hold sg==0
        float inv = rsqrtf(tot);
        out[1 + n*256 + d]         = zf;
        out[1 + 65536 + n*256 + d] = zf;
        Z[n*256 + d] = zf * inv;
    }
}

// loss = 2 - (2/255)*(||S||^2/256 - 1), S = sum_n zhat_n
__global__ __launch_bounds__(1024) void loss_kernel(const float* __restrict__ Z, float* __restrict__ out)
{
    __shared__ float sp[4][256];
    __shared__ float w4[16];
    const int tid = threadIdx.x;
    const int g = tid >> 8, d = tid & 255;
    float S = 0.f;
    #pragma unroll 8
    for (int n = g*64; n < g*64 + 64; ++n) S += Z[n*256 + d];
    sp[g][d] = S;
    __syncthreads();
    float v = 0.f;
    if (g == 0) {
        S = sp[0][d] + sp[1][d] + sp[2][d] + sp[3][d];
        v = S * S;
    }
    #pragma unroll
    for (int off = 32; off > 0; off >>= 1) v += __shfl_down(v, off, 64);
    if ((tid & 63) == 0) w4[tid >> 6] = v;
    __syncthreads();
    if (tid == 0) {
        float tot = w4[0] + w4[1] + w4[2] + w4[3];
        out[0] = 2.0f - (2.0f / 255.0f) * (tot * (1.0f / 256.0f) - 1.0f);
    }
}

extern "C" void kernel_launch(void* const* d_in, const int* in_sizes, int n_in,
                              void* d_out, int out_size, void* d_ws, size_t ws_size,
                              hipStream_t stream)
{
    (void)in_sizes; (void)n_in; (void)out_size; (void)ws_size;
    const float* x  = (const float*)d_in[0];
    const float* rw = (const float*)d_in[1];
    const float* sw = (const float*)d_in[2];
    const float* cw = (const float*)d_in[3];
    const float* W  = (const float*)d_in[4];
    const float* bb = (const float*)d_in[5];
    const float* Rr = (const float*)d_in[6];
    const float* Rs = (const float*)d_in[7];
    const float* Rc = (const float*)d_in[8];
    float* out = (float*)d_out;
    float* P = (float*)d_ws;                        // 225 * 65536 fp32 partials
    float* Z = P + (size_t)225 * 65536;             // 65536 fp32 zhat

    gemm_kernel<<<225, 512, 0, stream>>>(x, rw, sw, cw, W, Rr, Rs, Rc, P);
    reduce_kernel<<<256, 1024, 0, stream>>>(P, bb, out, Z);
    loss_kernel<<<1, 1024, 0, stream>>>(Z, out);
}